// Round 1
// baseline (340.981 us; speedup 1.0000x reference)
//
#include <hip/hip_runtime.h>

#define BN 512
#define VN 6890
#define JN 24
#define NBETA 10
#define PFD 207      // (J-1)*9
#define NCOL 20670   // V*3

// ---------------- Kernel 1: batch-independent joint constants ----------------
// jc[j][33]: [c*11 + 0] = JT0[j][c] = sum_v Jr[j,v]*vt[v,c]
//            [c*11 + 1 + k] = JS[j][c][k] = sum_v Jr[j,v]*sd[v,c,k]
__global__ void k_jc(const float* __restrict__ Jr, const float* __restrict__ vt,
                     const float* __restrict__ sd, float* __restrict__ jc) {
    int j = blockIdx.x;
    int tid = threadIdx.x;  // 256
    float acc[33];
#pragma unroll
    for (int i = 0; i < 33; ++i) acc[i] = 0.f;
    for (int v = tid; v < VN; v += 256) {
        float w = Jr[j * VN + v];
        const float* vtp = vt + v * 3;
        const float* sdp = sd + v * 30;
#pragma unroll
        for (int c = 0; c < 3; ++c) {
            acc[c * 11] += w * vtp[c];
#pragma unroll
            for (int k = 0; k < 10; ++k) acc[c * 11 + 1 + k] += w * sdp[c * 10 + k];
        }
    }
#pragma unroll
    for (int i = 0; i < 33; ++i) {
        float x = acc[i];
        for (int m = 32; m >= 1; m >>= 1) x += __shfl_xor(x, m, 64);
        acc[i] = x;
    }
    __shared__ float red[4][33];
    int wave = tid >> 6, lane = tid & 63;
    if (lane == 0) {
#pragma unroll
        for (int i = 0; i < 33; ++i) red[wave][i] = acc[i];
    }
    __syncthreads();
    if (tid < 33) jc[j * 33 + tid] = red[0][tid] + red[1][tid] + red[2][tid] + red[3][tid];
}

// ---------------- Kernel 2: per-batch rodrigues + chain + A ----------------
// outputs: pf[b][207], A[b][24*12]  (3x4 row-major per joint)
__global__ void k_batch(const float* __restrict__ pose, const float* __restrict__ betas,
                        const int* __restrict__ parents, const float* __restrict__ jc,
                        float* __restrict__ pf_out, float* __restrict__ A_out) {
    int b = blockIdx.x;
    int tid = threadIdx.x;  // 64
    __shared__ float rot[JN][9];
    __shared__ float Jts[JN][3];
    __shared__ float Tw[JN][12];
    __shared__ int par[JN];
    if (tid < JN) par[tid] = parents[tid];
    if (tid < JN) {
        int j = tid;
        float rx = pose[b * 72 + j * 3 + 0];
        float ry = pose[b * 72 + j * 3 + 1];
        float rz = pose[b * 72 + j * 3 + 2];
        float angle = sqrtf(rx * rx + ry * ry + rz * rz + 1e-16f);
        float inv = 1.f / angle;
        float x = rx * inv, y = ry * inv, z = rz * inv;
        float s = sinf(angle), c = cosf(angle);
        float C = 1.f - c;
        rot[j][0] = c + C * x * x;
        rot[j][1] = C * x * y - s * z;
        rot[j][2] = C * x * z + s * y;
        rot[j][3] = C * x * y + s * z;
        rot[j][4] = c + C * y * y;
        rot[j][5] = C * y * z - s * x;
        rot[j][6] = C * x * z - s * y;
        rot[j][7] = C * y * z + s * x;
        rot[j][8] = c + C * z * z;
        const float* jcj = jc + j * 33;
#pragma unroll
        for (int ci = 0; ci < 3; ++ci) {
            float t = jcj[ci * 11];
#pragma unroll
            for (int k = 0; k < 10; ++k) t += betas[b * 10 + k] * jcj[ci * 11 + 1 + k];
            Jts[j][ci] = t;
        }
    }
    __syncthreads();
    // pose_feature
    for (int idx = tid; idx < PFD; idx += 64) {
        int j = idx / 9 + 1;
        int e = idx % 9;
        float vI = (e == 0 || e == 4 || e == 8) ? 1.f : 0.f;
        pf_out[b * PFD + idx] = rot[j][e] - vI;
    }
    // chain root
    if (tid < 12) {
        int r = tid >> 2, cc = tid & 3;
        Tw[0][tid] = (cc < 3) ? rot[0][r * 3 + cc] : Jts[0][r];
    }
    __syncthreads();
    for (int i = 1; i < JN; ++i) {
        if (tid < 12) {
            int p = par[i];
            int r = tid >> 2, cc = tid & 3;
            float val;
            if (cc < 3) {
                val = Tw[p][r * 4 + 0] * rot[i][0 * 3 + cc] +
                      Tw[p][r * 4 + 1] * rot[i][1 * 3 + cc] +
                      Tw[p][r * 4 + 2] * rot[i][2 * 3 + cc];
            } else {
                float t0 = Jts[i][0] - Jts[p][0];
                float t1 = Jts[i][1] - Jts[p][1];
                float t2 = Jts[i][2] - Jts[p][2];
                val = Tw[p][r * 4 + 0] * t0 + Tw[p][r * 4 + 1] * t1 +
                      Tw[p][r * 4 + 2] * t2 + Tw[p][r * 4 + 3];
            }
            Tw[i][tid] = val;
        }
        __syncthreads();
    }
    if (tid < JN) {
        int j = tid;
        float Ar[12];
#pragma unroll
        for (int r = 0; r < 3; ++r) {
#pragma unroll
            for (int cc = 0; cc < 3; ++cc) Ar[r * 4 + cc] = Tw[j][r * 4 + cc];
            Ar[r * 4 + 3] = Tw[j][r * 4 + 3] -
                            (Tw[j][r * 4 + 0] * Jts[j][0] + Tw[j][r * 4 + 1] * Jts[j][1] +
                             Tw[j][r * 4 + 2] * Jts[j][2]);
        }
#pragma unroll
        for (int e = 0; e < 12; ++e) A_out[(b * JN + j) * 12 + e] = Ar[e];
    }
}

// ---------------- Kernel 3: fused shape + pose-GEMM + skinning ----------------
// grid (ceil(V/256), B/8), block 256. thread = one vertex, 8 batches.
#define BT 8
__global__ void __launch_bounds__(256)
k_skin(const float* __restrict__ betas, const float* __restrict__ trans,
       const float* __restrict__ vt, const float* __restrict__ sd,
       const float* __restrict__ pd, const float* __restrict__ wts,
       const float* __restrict__ pf, const float* __restrict__ Ag,
       float* __restrict__ out) {
    int tid = threadIdx.x;
    int v = blockIdx.x * 256 + tid;
    int b0 = blockIdx.y * BT;

    __shared__ __align__(16) float pf_s[BT][208];
    __shared__ float A_s[BT][288];
    __shared__ float bet_s[BT][NBETA];
    __shared__ float tr_s[BT][3];

    for (int i = tid; i < BT * PFD; i += 256) pf_s[i / PFD][i % PFD] = pf[(size_t)(b0 + i / PFD) * PFD + i % PFD];
    for (int i = tid; i < BT * 288; i += 256) A_s[i / 288][i % 288] = Ag[(size_t)(b0 + i / 288) * 288 + i % 288];
    for (int i = tid; i < BT * NBETA; i += 256) bet_s[i / NBETA][i % NBETA] = betas[(b0 + i / NBETA) * NBETA + i % NBETA];
    for (int i = tid; i < BT * 3; i += 256) tr_s[i / 3][i % 3] = trans[(b0 + i / 3) * 3 + i % 3];
    __syncthreads();
    if (v >= VN) return;

    // shaped template: acc[bi] = vt[v] + shapedirs[v] @ betas[b]
    float sdv[30];
#pragma unroll
    for (int i = 0; i < 30; ++i) sdv[i] = sd[v * 30 + i];
    float vt0 = vt[v * 3 + 0], vt1 = vt[v * 3 + 1], vt2 = vt[v * 3 + 2];
    float acc[BT][3];
#pragma unroll
    for (int bi = 0; bi < BT; ++bi) {
        float a0 = vt0, a1 = vt1, a2 = vt2;
#pragma unroll
        for (int k = 0; k < NBETA; ++k) {
            float be = bet_s[bi][k];
            a0 += be * sdv[k];
            a1 += be * sdv[10 + k];
            a2 += be * sdv[20 + k];
        }
        acc[bi][0] = a0; acc[bi][1] = a1; acc[bi][2] = a2;
    }

    // pose blendshape GEMM: acc[bi][c] += sum_k pf[b,k] * posedirs[k, v*3+c]
    const float* pdv = pd + (size_t)v * 3;
    int k4 = 0;
    for (; k4 + 4 <= 204; k4 += 4) {
        float4 pfv[BT];
#pragma unroll
        for (int bi = 0; bi < BT; ++bi) pfv[bi] = *(const float4*)&pf_s[bi][k4];
#pragma unroll
        for (int kk = 0; kk < 4; ++kk) {
            const float* row = pdv + (size_t)(k4 + kk) * NCOL;
            float p0 = row[0], p1 = row[1], p2 = row[2];
#pragma unroll
            for (int bi = 0; bi < BT; ++bi) {
                float f = (kk == 0) ? pfv[bi].x : (kk == 1) ? pfv[bi].y : (kk == 2) ? pfv[bi].z : pfv[bi].w;
                acc[bi][0] += f * p0;
                acc[bi][1] += f * p1;
                acc[bi][2] += f * p2;
            }
        }
    }
    for (int k = 204; k < PFD; ++k) {
        const float* row = pdv + (size_t)k * NCOL;
        float p0 = row[0], p1 = row[1], p2 = row[2];
#pragma unroll
        for (int bi = 0; bi < BT; ++bi) {
            float f = pf_s[bi][k];
            acc[bi][0] += f * p0;
            acc[bi][1] += f * p1;
            acc[bi][2] += f * p2;
        }
    }

    // skinning
    float w[JN];
#pragma unroll
    for (int j = 0; j < JN; ++j) w[j] = wts[(size_t)v * JN + j];
#pragma unroll
    for (int bi = 0; bi < BT; ++bi) {
        float T[12];
#pragma unroll
        for (int e = 0; e < 12; ++e) T[e] = 0.f;
#pragma unroll
        for (int j = 0; j < JN; ++j) {
            float wj = w[j];
            const float* Aj = &A_s[bi][j * 12];
#pragma unroll
            for (int e = 0; e < 12; ++e) T[e] += wj * Aj[e];
        }
        float x = acc[bi][0], y = acc[bi][1], z = acc[bi][2];
        int b = b0 + bi;
        float o0 = T[0] * x + T[1] * y + T[2]  * z + T[3]  + tr_s[bi][0];
        float o1 = T[4] * x + T[5] * y + T[6]  * z + T[7]  + tr_s[bi][1];
        float o2 = T[8] * x + T[9] * y + T[10] * z + T[11] + tr_s[bi][2];
        float* op = out + ((size_t)b * VN + v) * 3;
        op[0] = o0; op[1] = o1; op[2] = o2;
    }
}

extern "C" void kernel_launch(void* const* d_in, const int* in_sizes, int n_in,
                              void* d_out, int out_size, void* d_ws, size_t ws_size,
                              hipStream_t stream) {
    const float* pose      = (const float*)d_in[0];
    const float* betas     = (const float*)d_in[1];
    const float* trans     = (const float*)d_in[2];
    const float* v_template= (const float*)d_in[3];
    const float* shapedirs = (const float*)d_in[4];
    const float* posedirs  = (const float*)d_in[5];
    const float* Jreg      = (const float*)d_in[6];
    const float* weights   = (const float*)d_in[7];
    const int*   parents   = (const int*)d_in[8];
    float* out = (float*)d_out;
    float* ws  = (float*)d_ws;

    float* jc = ws;                      // 24*33 = 792 floats
    float* pf = ws + 1024;               // 512*207 = 105984
    float* A  = ws + 1024 + 105984;      // 512*288 = 147456

    hipLaunchKernelGGL(k_jc, dim3(JN), dim3(256), 0, stream, Jreg, v_template, shapedirs, jc);
    hipLaunchKernelGGL(k_batch, dim3(BN), dim3(64), 0, stream, pose, betas, parents, jc, pf, A);
    hipLaunchKernelGGL(k_skin, dim3((VN + 255) / 256, BN / BT), dim3(256), 0, stream,
                       betas, trans, v_template, shapedirs, posedirs, weights, pf, A, out);
}